// Round 1
// baseline (833.715 us; speedup 1.0000x reference)
//
#include <hip/hip_runtime.h>

#define DI 256
#define DO 256

typedef float f32x4 __attribute__((ext_vector_type(4)));
typedef __bf16 bf16x8 __attribute__((ext_vector_type(8)));

__device__ __forceinline__ float b2f(unsigned short u) {
    union { unsigned int i; float f; } v; v.i = ((unsigned int)u) << 16; return v.f;
}
__device__ __forceinline__ unsigned short f2b(float f) {
    unsigned int x = __float_as_uint(f);
    unsigned int r = x + 0x7FFFu + ((x >> 16) & 1u);
    return (unsigned short)(r >> 16);
}

// ---------------- prep: x -> bf16 ----------------
__global__ __launch_bounds__(256) void conv_x_kernel(const float* __restrict__ x,
                                                     unsigned short* __restrict__ xb, int total8) {
    int gid = blockIdx.x * 256 + threadIdx.x;
    if (gid >= total8) return;
    size_t idx = (size_t)gid * 8;
    float4 v0 = *(const float4*)(x + idx);
    float4 v1 = *(const float4*)(x + idx + 4);
    ushort4 o0, o1;
    o0.x = f2b(v0.x); o0.y = f2b(v0.y); o0.z = f2b(v0.z); o0.w = f2b(v0.w);
    o1.x = f2b(v1.x); o1.y = f2b(v1.y); o1.z = f2b(v1.z); o1.w = f2b(v1.w);
    *(ushort4*)(xb + idx) = o0;
    *(ushort4*)(xb + idx + 4) = o1;
}

// ---------------- prep: W -> bf16, transposed to [n][k] ----------------
__global__ __launch_bounds__(256) void prep_w_kernel(const float* __restrict__ W1, const float* __restrict__ W2,
                                                     unsigned short* __restrict__ w1t, unsigned short* __restrict__ w2t) {
    int gid = blockIdx.x * 256 + threadIdx.x;   // 512*256 = 131072 threads
    int which = gid >> 16;
    int idx = gid & 65535;
    int n = idx >> 8, k = idx & 255;
    const float* W = which ? W2 : W1;
    unsigned short* O = which ? w2t : w1t;
    O[n * 256 + k] = f2b(W[k * 256 + n]);
}

// ---------------- CSR build ----------------
__global__ __launch_bounds__(256) void hist_kernel(const int* __restrict__ er, int* __restrict__ counts, int E) {
    for (int e = blockIdx.x * blockDim.x + threadIdx.x; e < E; e += gridDim.x * blockDim.x)
        atomicAdd(&counts[er[e]], 1);
}

__global__ __launch_bounds__(256) void scan1_kernel(const int* __restrict__ counts, int* __restrict__ bsum, int N) {
    int base = blockIdx.x * 1024;
    int t = threadIdx.x, lane = t & 63, w = t >> 6;
    int s = 0;
#pragma unroll
    for (int j = 0; j < 4; ++j) {
        int idx = base + t * 4 + j;
        s += (idx < N) ? counts[idx] : 0;
    }
#pragma unroll
    for (int off = 1; off < 64; off <<= 1) s += __shfl_xor(s, off);
    __shared__ int red[4];
    if (lane == 0) red[w] = s;
    __syncthreads();
    if (t == 0) bsum[blockIdx.x] = red[0] + red[1] + red[2] + red[3];
}

__global__ void scan2_kernel(int* __restrict__ bsum, int nb) {
    if (blockIdx.x == 0 && threadIdx.x == 0) {
        int acc = 0;
        for (int i = 0; i < nb; ++i) { int v = bsum[i]; bsum[i] = acc; acc += v; }
    }
}

__global__ __launch_bounds__(256) void scan3_kernel(const int* __restrict__ counts, const int* __restrict__ bsum,
                                                    int* __restrict__ row_start, int N) {
    int base = blockIdx.x * 1024;
    int t = threadIdx.x, lane = t & 63, w = t >> 6;
    int v[4]; int s = 0;
#pragma unroll
    for (int j = 0; j < 4; ++j) {
        int idx = base + t * 4 + j;
        v[j] = (idx < N) ? counts[idx] : 0;
        s += v[j];
    }
    int sinc = s;
#pragma unroll
    for (int off = 1; off < 64; off <<= 1) {
        int u = __shfl_up(sinc, off);
        if (lane >= off) sinc += u;
    }
    __shared__ int wsum[4];
    if (lane == 63) wsum[w] = sinc;
    __syncthreads();
    int woff = 0;
    for (int i = 0; i < w; ++i) woff += wsum[i];
    int excl = bsum[blockIdx.x] + woff + (sinc - s);
#pragma unroll
    for (int j = 0; j < 4; ++j) {
        int idx = base + t * 4 + j;
        if (idx < N) row_start[idx] = excl;
        excl += v[j];
    }
}

__global__ __launch_bounds__(256) void scatter_kernel(const int* __restrict__ er, const int* __restrict__ ec,
                                                      const float* __restrict__ ev, const int* __restrict__ row_start,
                                                      int* __restrict__ cursor, int2* __restrict__ cv, int E) {
    for (int e = blockIdx.x * blockDim.x + threadIdx.x; e < E; e += gridDim.x * blockDim.x) {
        int r = er[e];
        int p = row_start[r] + atomicAdd(&cursor[r], 1);
        cv[p] = make_int2(ec[e], __float_as_int(ev[e]));
    }
}

// ---------------- SpMM + self-loop combine: h0 = (1+eps)*x + A@x  (bf16 out) ----------------
__global__ __launch_bounds__(256) void spmm_kernel(const unsigned short* __restrict__ xb, const int2* __restrict__ cv,
                                                   const int* __restrict__ row_start, const int* __restrict__ counts,
                                                   const float* __restrict__ epsp, unsigned short* __restrict__ h0, int N) {
    int node = blockIdx.x * 4 + (threadIdx.x >> 6);
    int lane = threadIdx.x & 63;
    if (node >= N) return;
    int start = row_start[node];
    int deg = counts[node];
    float a0 = 0.f, a1 = 0.f, a2 = 0.f, a3 = 0.f;
    int2 cA = (deg > 0) ? cv[start] : make_int2(0, 0);
    int2 cB = (deg > 1) ? cv[start + 1] : make_int2(0, 0);
    ushort4 xA = (deg > 0) ? *(const ushort4*)(xb + (size_t)cA.x * 256 + lane * 4) : ushort4{0, 0, 0, 0};
    for (int e = 0; e < deg; ++e) {
        int2 cC = (e + 2 < deg) ? cv[start + e + 2] : make_int2(0, 0);
        ushort4 xB = (e + 1 < deg) ? *(const ushort4*)(xb + (size_t)cB.x * 256 + lane * 4) : ushort4{0, 0, 0, 0};
        float v = __int_as_float(cA.y);
        a0 += v * b2f(xA.x);
        a1 += v * b2f(xA.y);
        a2 += v * b2f(xA.z);
        a3 += v * b2f(xA.w);
        cA = cB; cB = cC; xA = xB;
    }
    float ep = 1.0f + epsp[0];
    ushort4 xo = *(const ushort4*)(xb + (size_t)node * 256 + lane * 4);
    ushort4 o;
    o.x = f2b(ep * b2f(xo.x) + a0);
    o.y = f2b(ep * b2f(xo.y) + a1);
    o.z = f2b(ep * b2f(xo.z) + a2);
    o.w = f2b(ep * b2f(xo.w) + a3);
    *(ushort4*)(h0 + (size_t)node * 256 + lane * 4) = o;
}

// ---------------- GEMM (bf16 MFMA) + bias + BN-stat accumulation ----------------
// Y[r][c] = sum_k A[r][k]*Wt[c][k] + bias[c]; stats[c] += sum_r Y, stats[256+c] += sum_r Y^2
// BM=64 rows/block, BN=256 (full width), BK=64, 4 waves (2m x 2n), wave tile 32x128.
__global__ __launch_bounds__(256) void gemm_bn_kernel(const unsigned short* __restrict__ A,
                                                      const unsigned short* __restrict__ Wt,
                                                      const float* __restrict__ bias,
                                                      unsigned short* __restrict__ Y,
                                                      float* __restrict__ stats, int N) {
    __shared__ unsigned short As[64 * 64];    // [row][k] rows 128B, XOR-swizzled
    __shared__ unsigned short Bs[256 * 64];   // [n][k]  rows 128B, XOR-swizzled
    __shared__ float red[4][2][128];

    const int t = threadIdx.x, lane = t & 63, w = t >> 6;
    const int wm = w >> 1, wn = w & 1;
    const long row0 = (long)blockIdx.x * 64;

    f32x4 acc[2][8];
#pragma unroll
    for (int i = 0; i < 2; ++i)
#pragma unroll
        for (int j = 0; j < 8; ++j) acc[i][j] = (f32x4){0.f, 0.f, 0.f, 0.f};

    for (int ks = 0; ks < 4; ++ks) {
        if (ks) __syncthreads();
        // stage A tile: 64 rows x 64 k (8KB) — 2 x 16B chunks per thread
#pragma unroll
        for (int i = 0; i < 2; ++i) {
            int c = t + i * 256;
            int r = c >> 3, cb = (c & 7) << 4;
            uint4 d = *(const uint4*)(A + (row0 + r) * 256 + ks * 64 + (cb >> 1));
            *(uint4*)((char*)As + r * 128 + (cb ^ ((r & 7) << 4))) = d;
        }
        // stage B tile: 256 n x 64 k (32KB) — 8 x 16B chunks per thread
#pragma unroll
        for (int i = 0; i < 8; ++i) {
            int c = t + i * 256;
            int n = c >> 3, cb = (c & 7) << 4;
            uint4 d = *(const uint4*)(Wt + n * 256 + ks * 64 + (cb >> 1));
            *(uint4*)((char*)Bs + n * 128 + (cb ^ ((n & 7) << 4))) = d;
        }
        __syncthreads();
#pragma unroll
        for (int k2 = 0; k2 < 2; ++k2) {
            bf16x8 af[2];
#pragma unroll
            for (int mf = 0; mf < 2; ++mf) {
                int r = wm * 32 + mf * 16 + (lane & 15);
                int cb = k2 * 64 + ((lane >> 4) << 4);
                af[mf] = *(const bf16x8*)((const char*)As + r * 128 + (cb ^ ((r & 7) << 4)));
            }
#pragma unroll
            for (int nf = 0; nf < 8; ++nf) {
                int n = wn * 128 + nf * 16 + (lane & 15);
                int cb = k2 * 64 + ((lane >> 4) << 4);
                bf16x8 bfr = *(const bf16x8*)((const char*)Bs + n * 128 + (cb ^ ((n & 7) << 4)));
                acc[0][nf] = __builtin_amdgcn_mfma_f32_16x16x32_bf16(af[0], bfr, acc[0][nf], 0, 0, 0);
                acc[1][nf] = __builtin_amdgcn_mfma_f32_16x16x32_bf16(af[1], bfr, acc[1][nf], 0, 0, 0);
            }
        }
    }

    // epilogue: bias, bf16 store (masked), per-column sum/sumsq
    float csum[8], csq[8];
#pragma unroll
    for (int nf = 0; nf < 8; ++nf) { csum[nf] = 0.f; csq[nf] = 0.f; }
#pragma unroll
    for (int nf = 0; nf < 8; ++nf) {
        int col = wn * 128 + nf * 16 + (lane & 15);
        float b = bias[col];
#pragma unroll
        for (int mf = 0; mf < 2; ++mf) {
#pragma unroll
            for (int reg = 0; reg < 4; ++reg) {
                long r = row0 + wm * 32 + mf * 16 + ((lane >> 4) << 2) + reg;
                if (r < N) {
                    float y = acc[mf][nf][reg] + b;
                    Y[r * 256 + col] = f2b(y);
                    csum[nf] += y;
                    csq[nf] += y * y;
                }
            }
        }
    }
#pragma unroll
    for (int nf = 0; nf < 8; ++nf) {
        csum[nf] += __shfl_xor(csum[nf], 16);
        csum[nf] += __shfl_xor(csum[nf], 32);
        csq[nf] += __shfl_xor(csq[nf], 16);
        csq[nf] += __shfl_xor(csq[nf], 32);
    }
    if (lane < 16) {
#pragma unroll
        for (int nf = 0; nf < 8; ++nf) {
            red[w][0][nf * 16 + lane] = csum[nf];
            red[w][1][nf * 16 + lane] = csq[nf];
        }
    }
    __syncthreads();
    {
        int c = t;              // 256 block columns
        int wnc = c >> 7, cc = c & 127;
        float s = red[wnc][0][cc] + red[2 + wnc][0][cc];
        float q = red[wnc][1][cc] + red[2 + wnc][1][cc];
        atomicAdd(&stats[c], s);
        atomicAdd(&stats[256 + c], q);
    }
}

// ---------------- BN finalize: per-column scale/shift ----------------
__global__ void finalize_kernel(const float* __restrict__ stats, const float* __restrict__ g,
                                const float* __restrict__ be, float* __restrict__ coef, float invN) {
    int c = threadIdx.x;
    float mean = stats[c] * invN;
    float var = stats[256 + c] * invN - mean * mean;
    float rs = rsqrtf(var + 1e-5f);
    float a = g[c] * rs;
    coef[c] = a;
    coef[256 + c] = be[c] - mean * a;
}

// ---------------- BN apply + ReLU, in-place on bf16 buffer ----------------
__global__ __launch_bounds__(256) void bnrelu_ip_kernel(unsigned short* __restrict__ y,
                                                        const float* __restrict__ coef, int total) {
    int gid = blockIdx.x * 256 + threadIdx.x;
    if (gid >= total) return;
    int r = gid >> 5, s = gid & 31;
    size_t idx = (size_t)r * 256 + s * 8;
    uint4 v = *(const uint4*)(y + idx);
    float4 a0 = *(const float4*)(coef + s * 8);
    float4 a1 = *(const float4*)(coef + s * 8 + 4);
    float4 c0 = *(const float4*)(coef + 256 + s * 8);
    float4 c1 = *(const float4*)(coef + 256 + s * 8 + 4);
    unsigned int vv[4] = {v.x, v.y, v.z, v.w};
    float av[8] = {a0.x, a0.y, a0.z, a0.w, a1.x, a1.y, a1.z, a1.w};
    float cvf[8] = {c0.x, c0.y, c0.z, c0.w, c1.x, c1.y, c1.z, c1.w};
    unsigned int ov[4];
#pragma unroll
    for (int j = 0; j < 4; ++j) {
        float lo = b2f((unsigned short)(vv[j] & 0xffff));
        float hi = b2f((unsigned short)(vv[j] >> 16));
        float o0 = fmaxf(0.f, lo * av[2 * j] + cvf[2 * j]);
        float o1 = fmaxf(0.f, hi * av[2 * j + 1] + cvf[2 * j + 1]);
        ov[j] = (unsigned int)f2b(o0) | ((unsigned int)f2b(o1) << 16);
    }
    uint4 o = {ov[0], ov[1], ov[2], ov[3]};
    *(uint4*)(y + idx) = o;
}

// ---------------- BN apply + ReLU, f32 output ----------------
__global__ __launch_bounds__(256) void bnrelu_out_kernel(const unsigned short* __restrict__ y,
                                                         const float* __restrict__ coef,
                                                         float* __restrict__ out, int total) {
    int gid = blockIdx.x * 256 + threadIdx.x;
    if (gid >= total) return;
    int r = gid >> 5, s = gid & 31;
    size_t idx = (size_t)r * 256 + s * 8;
    uint4 v = *(const uint4*)(y + idx);
    float4 a0 = *(const float4*)(coef + s * 8);
    float4 a1 = *(const float4*)(coef + s * 8 + 4);
    float4 c0 = *(const float4*)(coef + 256 + s * 8);
    float4 c1 = *(const float4*)(coef + 256 + s * 8 + 4);
    unsigned int vv[4] = {v.x, v.y, v.z, v.w};
    float av[8] = {a0.x, a0.y, a0.z, a0.w, a1.x, a1.y, a1.z, a1.w};
    float cvf[8] = {c0.x, c0.y, c0.z, c0.w, c1.x, c1.y, c1.z, c1.w};
    float o[8];
#pragma unroll
    for (int j = 0; j < 4; ++j) {
        float lo = b2f((unsigned short)(vv[j] & 0xffff));
        float hi = b2f((unsigned short)(vv[j] >> 16));
        o[2 * j] = fmaxf(0.f, lo * av[2 * j] + cvf[2 * j]);
        o[2 * j + 1] = fmaxf(0.f, hi * av[2 * j + 1] + cvf[2 * j + 1]);
    }
    float4 w0 = {o[0], o[1], o[2], o[3]};
    float4 w1 = {o[4], o[5], o[6], o[7]};
    *(float4*)(out + idx) = w0;
    *(float4*)(out + idx + 4) = w1;
}

extern "C" void kernel_launch(void* const* d_in, const int* in_sizes, int n_in,
                              void* d_out, int out_size, void* d_ws, size_t ws_size,
                              hipStream_t stream) {
    const float* x   = (const float*)d_in[0];
    const int*   er  = (const int*)d_in[1];
    const int*   ec  = (const int*)d_in[2];
    const float* ev  = (const float*)d_in[3];
    const float* eps = (const float*)d_in[4];
    const float* W1  = (const float*)d_in[5];
    const float* b1  = (const float*)d_in[6];
    const float* g1  = (const float*)d_in[7];
    const float* be1 = (const float*)d_in[8];
    const float* W2  = (const float*)d_in[9];
    const float* b2  = (const float*)d_in[10];
    const float* g2  = (const float*)d_in[11];
    const float* be2 = (const float*)d_in[12];

    const int N = in_sizes[0] / 256;      // 100000
    const int E = in_sizes[1];            // 3200000
    const int Npad = ((N + 63) / 64) * 64;

    // workspace layout
    char* ws = (char*)d_ws;
    size_t off = 0;
    auto alloc = [&](size_t bytes) { size_t cur = off; off = (off + bytes + 255) & ~(size_t)255; return cur; };
    size_t o_counts = alloc((size_t)N * 4);
    size_t o_cursor = alloc((size_t)N * 4);
    size_t o_stats  = alloc(4096);
    size_t zbytes   = off;                 // zero counts+cursor+stats each call
    size_t o_rowst  = alloc((size_t)(N + 1) * 4);
    size_t o_coef   = alloc(4096);
    size_t o_bsum   = alloc(1024);
    size_t o_cv     = alloc((size_t)E * 8);
    size_t o_xb     = alloc((size_t)N * 256 * 2);
    size_t o_h0     = alloc((size_t)Npad * 256 * 2);
    size_t o_y1     = alloc((size_t)Npad * 256 * 2);
    size_t o_w1t    = alloc(65536 * 2);
    size_t o_w2t    = alloc(65536 * 2);
    (void)ws_size;

    int* counts = (int*)(ws + o_counts);
    int* cursor = (int*)(ws + o_cursor);
    float* stats = (float*)(ws + o_stats);
    int* row_start = (int*)(ws + o_rowst);
    float* coef = (float*)(ws + o_coef);
    int* bsum = (int*)(ws + o_bsum);
    int2* cv = (int2*)(ws + o_cv);
    unsigned short* xb = (unsigned short*)(ws + o_xb);
    unsigned short* h0 = (unsigned short*)(ws + o_h0);
    unsigned short* y1 = (unsigned short*)(ws + o_y1);
    unsigned short* w1t = (unsigned short*)(ws + o_w1t);
    unsigned short* w2t = (unsigned short*)(ws + o_w2t);

    hipMemsetAsync(ws, 0, zbytes, stream);

    int total8 = N * 32;                   // threads for 8-wide elementwise
    conv_x_kernel<<<(total8 + 255) / 256, 256, 0, stream>>>(x, xb, total8);
    prep_w_kernel<<<512, 256, 0, stream>>>(W1, W2, w1t, w2t);

    hist_kernel<<<2048, 256, 0, stream>>>(er, counts, E);
    int nb = (N + 1023) / 1024;
    scan1_kernel<<<nb, 256, 0, stream>>>(counts, bsum, N);
    scan2_kernel<<<1, 64, 0, stream>>>(bsum, nb);
    scan3_kernel<<<nb, 256, 0, stream>>>(counts, bsum, row_start, N);
    scatter_kernel<<<2048, 256, 0, stream>>>(er, ec, ev, row_start, cursor, cv, E);

    spmm_kernel<<<(N + 3) / 4, 256, 0, stream>>>(xb, cv, row_start, counts, eps, h0, N);

    float invN = 1.0f / (float)N;
    gemm_bn_kernel<<<Npad / 64, 256, 0, stream>>>(h0, w1t, b1, y1, stats, N);
    finalize_kernel<<<1, 256, 0, stream>>>(stats, g1, be1, coef, invN);
    bnrelu_ip_kernel<<<(total8 + 255) / 256, 256, 0, stream>>>(y1, coef, total8);

    gemm_bn_kernel<<<Npad / 64, 256, 0, stream>>>(y1, w2t, b2, h0, stats + 512, N);
    finalize_kernel<<<1, 256, 0, stream>>>(stats + 512, g2, be2, coef + 512, invN);
    bnrelu_out_kernel<<<(total8 + 255) / 256, 256, 0, stream>>>(h0, coef + 512, (float*)d_out, total8);
}

// Round 2
// 739.197 us; speedup vs baseline: 1.1279x; 1.1279x over previous
//
#include <hip/hip_runtime.h>

typedef float f32x4 __attribute__((ext_vector_type(4)));
typedef __bf16 bf16x8 __attribute__((ext_vector_type(8)));

__device__ __forceinline__ float b2f(unsigned short u) {
    union { unsigned int i; float f; } v; v.i = ((unsigned int)u) << 16; return v.f;
}
__device__ __forceinline__ unsigned short f2b(float f) {
    unsigned int x = __float_as_uint(f);
    unsigned int r = x + 0x7FFFu + ((x >> 16) & 1u);
    return (unsigned short)(r >> 16);
}
__device__ __forceinline__ float blo(unsigned int d) { return __uint_as_float(d << 16); }
__device__ __forceinline__ float bhi(unsigned int d) { return __uint_as_float(d & 0xffff0000u); }

__device__ __forceinline__ void gload_lds16(const void* g, void* l) {
    __builtin_amdgcn_global_load_lds((const __attribute__((address_space(1))) void*)g,
                                     (__attribute__((address_space(3))) void*)l, 16, 0, 0);
}

// ---------------- fused prep: x->bf16 | W->bf16 transposed | row histogram ----------------
__global__ __launch_bounds__(256) void prep_kernel(const float* __restrict__ x, unsigned short* __restrict__ xb, int total8,
                                                   const float* __restrict__ W1, const float* __restrict__ W2,
                                                   unsigned short* __restrict__ w1t, unsigned short* __restrict__ w2t,
                                                   const int* __restrict__ er, int* __restrict__ counts, int E,
                                                   int nconv, int nhist) {
    int b = blockIdx.x, t = threadIdx.x;
    if (b < nconv) {
        int gid = b * 256 + t;
        if (gid >= total8) return;
        size_t idx = (size_t)gid * 8;
        float4 v0 = *(const float4*)(x + idx);
        float4 v1 = *(const float4*)(x + idx + 4);
        ushort4 o0, o1;
        o0.x = f2b(v0.x); o0.y = f2b(v0.y); o0.z = f2b(v0.z); o0.w = f2b(v0.w);
        o1.x = f2b(v1.x); o1.y = f2b(v1.y); o1.z = f2b(v1.z); o1.w = f2b(v1.w);
        *(ushort4*)(xb + idx) = o0;
        *(ushort4*)(xb + idx + 4) = o1;
    } else if (b < nconv + 512) {
        int gid = (b - nconv) * 256 + t;     // 131072 = 2 * 65536
        int which = gid >> 16;
        int idx = gid & 65535;
        int n = idx >> 8, k = idx & 255;
        const float* W = which ? W2 : W1;
        unsigned short* O = which ? w2t : w1t;
        O[n * 256 + k] = f2b(W[k * 256 + n]);
    } else {
        int e0 = (b - nconv - 512) * 256 + t;
        int step = nhist * 256;
        for (int e = e0; e < E; e += step)
            atomicAdd(&counts[er[e]], 1);
    }
}

// ---------------- scan (row_start from counts) ----------------
__global__ __launch_bounds__(256) void scan1_kernel(const int* __restrict__ counts, int* __restrict__ bsum, int N) {
    int base = blockIdx.x * 1024;
    int t = threadIdx.x, lane = t & 63, w = t >> 6;
    int s = 0;
#pragma unroll
    for (int j = 0; j < 4; ++j) {
        int idx = base + t * 4 + j;
        s += (idx < N) ? counts[idx] : 0;
    }
#pragma unroll
    for (int off = 1; off < 64; off <<= 1) s += __shfl_xor(s, off);
    __shared__ int red[4];
    if (lane == 0) red[w] = s;
    __syncthreads();
    if (t == 0) bsum[blockIdx.x] = red[0] + red[1] + red[2] + red[3];
}

__global__ void scan2_kernel(int* __restrict__ bsum, int nb) {
    if (blockIdx.x == 0 && threadIdx.x == 0) {
        int acc = 0;
        for (int i = 0; i < nb; ++i) { int v = bsum[i]; bsum[i] = acc; acc += v; }
    }
}

__global__ __launch_bounds__(256) void scan3_kernel(const int* __restrict__ counts, const int* __restrict__ bsum,
                                                    int* __restrict__ row_start, int N) {
    int base = blockIdx.x * 1024;
    int t = threadIdx.x, lane = t & 63, w = t >> 6;
    int v[4]; int s = 0;
#pragma unroll
    for (int j = 0; j < 4; ++j) {
        int idx = base + t * 4 + j;
        v[j] = (idx < N) ? counts[idx] : 0;
        s += v[j];
    }
    int sinc = s;
#pragma unroll
    for (int off = 1; off < 64; off <<= 1) {
        int u = __shfl_up(sinc, off);
        if (lane >= off) sinc += u;
    }
    __shared__ int wsum[4];
    if (lane == 63) wsum[w] = sinc;
    __syncthreads();
    int woff = 0;
    for (int i = 0; i < w; ++i) woff += wsum[i];
    int excl = bsum[blockIdx.x] + woff + (sinc - s);
#pragma unroll
    for (int j = 0; j < 4; ++j) {
        int idx = base + t * 4 + j;
        if (idx < N) row_start[idx] = excl;
        excl += v[j];
    }
}

__global__ __launch_bounds__(256) void scatter_kernel(const int* __restrict__ er, const int* __restrict__ ec,
                                                      const float* __restrict__ ev, const int* __restrict__ row_start,
                                                      int* __restrict__ cursor, int2* __restrict__ cv, int E) {
    for (int e = blockIdx.x * blockDim.x + threadIdx.x; e < E; e += gridDim.x * blockDim.x) {
        int r = er[e];
        int p = row_start[r] + atomicAdd(&cursor[r], 1);
        cv[p] = make_int2(ec[e], __float_as_int(ev[e]));
    }
}

// ---------------- SpMM + self-loop: h0 = (1+eps)*x + A@x  (bf16 out) ----------------
// One node per wave. Edge (col,val) are wave-uniform: cooperative 64-edge load,
// readlane -> SGPR col/val, SALU base address, 4 gathers in flight per group.
#define ACC4(d, v) { a0 += (v) * blo((d).x); a1 += (v) * bhi((d).x); \
                     a2 += (v) * blo((d).y); a3 += (v) * bhi((d).y); }

__global__ __launch_bounds__(256) void spmm_kernel(const unsigned short* __restrict__ xb, const int2* __restrict__ cv,
                                                   const int* __restrict__ row_start, const int* __restrict__ counts,
                                                   const float* __restrict__ epsp, unsigned short* __restrict__ h0, int N) {
    int node = blockIdx.x * 4 + (threadIdx.x >> 6);
    int lane = threadIdx.x & 63;
    if (node >= N) return;
    int start = __builtin_amdgcn_readfirstlane(row_start[node]);
    int deg   = __builtin_amdgcn_readfirstlane(counts[node]);
    const char* xbb = (const char*)xb;
    int voff = lane * 8;
    float a0 = 0.f, a1 = 0.f, a2 = 0.f, a3 = 0.f;

    for (int base = 0; base < deg; base += 64) {
        int rem = deg - base; if (rem > 64) rem = 64;
        int2 my = make_int2(0, 0);
        if (lane < rem) my = cv[start + base + lane];
        int j = 0;
        for (; j + 4 <= rem; j += 4) {
            int c0 = __builtin_amdgcn_readlane(my.x, j + 0);
            int c1 = __builtin_amdgcn_readlane(my.x, j + 1);
            int c2 = __builtin_amdgcn_readlane(my.x, j + 2);
            int c3 = __builtin_amdgcn_readlane(my.x, j + 3);
            float v0 = __int_as_float(__builtin_amdgcn_readlane(my.y, j + 0));
            float v1 = __int_as_float(__builtin_amdgcn_readlane(my.y, j + 1));
            float v2 = __int_as_float(__builtin_amdgcn_readlane(my.y, j + 2));
            float v3 = __int_as_float(__builtin_amdgcn_readlane(my.y, j + 3));
            uint2 d0 = *(const uint2*)(xbb + (size_t)c0 * 512 + voff);
            uint2 d1 = *(const uint2*)(xbb + (size_t)c1 * 512 + voff);
            uint2 d2 = *(const uint2*)(xbb + (size_t)c2 * 512 + voff);
            uint2 d3 = *(const uint2*)(xbb + (size_t)c3 * 512 + voff);
            ACC4(d0, v0); ACC4(d1, v1); ACC4(d2, v2); ACC4(d3, v3);
        }
        for (; j < rem; ++j) {
            int c0 = __builtin_amdgcn_readlane(my.x, j);
            float v0 = __int_as_float(__builtin_amdgcn_readlane(my.y, j));
            uint2 d0 = *(const uint2*)(xbb + (size_t)c0 * 512 + voff);
            ACC4(d0, v0);
        }
    }

    float ep = 1.0f + epsp[0];
    uint2 xo = *(const uint2*)(xbb + (size_t)node * 512 + voff);
    unsigned int w0 = ((unsigned int)f2b(ep * blo(xo.x) + a0)) | (((unsigned int)f2b(ep * bhi(xo.x) + a1)) << 16);
    unsigned int w1 = ((unsigned int)f2b(ep * blo(xo.y) + a2)) | (((unsigned int)f2b(ep * bhi(xo.y) + a3)) << 16);
    *(uint2*)((char*)h0 + (size_t)node * 512 + voff) = make_uint2(w0, w1);
}

// ---------------- GEMM (bf16 MFMA) + bias + BN-stat accumulation ----------------
// BM=128, BN=256 (full width), BK=64, 512 threads = 8 waves (4m x 2n), wave tile 32x128.
// Staging via global_load_lds(16B), linear LDS dest + pre-swizzled global source;
// reads use the same XOR swizzle (byte ^= (row&7)<<4).
__global__ __launch_bounds__(512, 4) void gemm_bn_kernel(const unsigned short* __restrict__ A,
                                                         const unsigned short* __restrict__ Wt,
                                                         const float* __restrict__ bias,
                                                         unsigned short* __restrict__ Y,
                                                         float* __restrict__ stats, int N) {
    __shared__ unsigned short As[128 * 64];   // 16 KB, rows 128B
    __shared__ unsigned short Bs[256 * 64];   // 32 KB
    __shared__ float red[8][2][128];          // 8 KB

    const int t = threadIdx.x, lane = t & 63, w = t >> 6;
    const int wm = w >> 1, wn = w & 1;        // wm 0..3, wn 0..1
    const long row0 = (long)blockIdx.x * 128;

    f32x4 acc[2][8];
#pragma unroll
    for (int i = 0; i < 2; ++i)
#pragma unroll
        for (int j = 0; j < 8; ++j) acc[i][j] = (f32x4){0.f, 0.f, 0.f, 0.f};

    const int lr = lane >> 3;                 // row within 8-row chunk
    const int cb0 = (lane & 7) << 4;          // linear byte slot in 128B row

    for (int ks = 0; ks < 4; ++ks) {
        if (ks) __syncthreads();
        // A tile: 16 chunks of 1KB (8 rows each); wave w stages chunks 2w, 2w+1
#pragma unroll
        for (int i = 0; i < 2; ++i) {
            int chunk = w * 2 + i;
            int r = chunk * 8 + lr;
            int sb = cb0 ^ ((r & 7) << 4);
            gload_lds16(A + (row0 + r) * 256 + ks * 64 + (sb >> 1), (char*)As + chunk * 1024);
        }
        // B tile: 32 chunks; wave w stages chunks 4w..4w+3
#pragma unroll
        for (int i = 0; i < 4; ++i) {
            int chunk = w * 4 + i;
            int n = chunk * 8 + lr;
            int sb = cb0 ^ ((n & 7) << 4);
            gload_lds16(Wt + n * 256 + ks * 64 + (sb >> 1), (char*)Bs + chunk * 1024);
        }
        __syncthreads();
#pragma unroll
        for (int k2 = 0; k2 < 2; ++k2) {
            int cb = k2 * 64 + ((lane >> 4) << 4);
            bf16x8 af[2];
#pragma unroll
            for (int mf = 0; mf < 2; ++mf) {
                int r = wm * 32 + mf * 16 + (lane & 15);
                af[mf] = *(const bf16x8*)((const char*)As + r * 128 + (cb ^ ((r & 7) << 4)));
            }
#pragma unroll
            for (int nf = 0; nf < 8; ++nf) {
                int n = wn * 128 + nf * 16 + (lane & 15);
                bf16x8 bfr = *(const bf16x8*)((const char*)Bs + n * 128 + (cb ^ ((n & 7) << 4)));
                acc[0][nf] = __builtin_amdgcn_mfma_f32_16x16x32_bf16(af[0], bfr, acc[0][nf], 0, 0, 0);
                acc[1][nf] = __builtin_amdgcn_mfma_f32_16x16x32_bf16(af[1], bfr, acc[1][nf], 0, 0, 0);
            }
        }
    }

    // epilogue: bias, bf16 store (masked), per-column sum/sumsq
    float csum[8], csq[8];
#pragma unroll
    for (int nf = 0; nf < 8; ++nf) { csum[nf] = 0.f; csq[nf] = 0.f; }
#pragma unroll
    for (int nf = 0; nf < 8; ++nf) {
        int col = wn * 128 + nf * 16 + (lane & 15);
        float b = bias[col];
#pragma unroll
        for (int mf = 0; mf < 2; ++mf) {
#pragma unroll
            for (int reg = 0; reg < 4; ++reg) {
                long r = row0 + wm * 32 + mf * 16 + ((lane >> 4) << 2) + reg;
                if (r < N) {
                    float y = acc[mf][nf][reg] + b;
                    Y[r * 256 + col] = f2b(y);
                    csum[nf] += y;
                    csq[nf] += y * y;
                }
            }
        }
    }
#pragma unroll
    for (int nf = 0; nf < 8; ++nf) {
        csum[nf] += __shfl_xor(csum[nf], 16);
        csum[nf] += __shfl_xor(csum[nf], 32);
        csq[nf] += __shfl_xor(csq[nf], 16);
        csq[nf] += __shfl_xor(csq[nf], 32);
    }
    if (lane < 16) {
#pragma unroll
        for (int nf = 0; nf < 8; ++nf) {
            red[w][0][nf * 16 + lane] = csum[nf];
            red[w][1][nf * 16 + lane] = csq[nf];
        }
    }
    __syncthreads();
    if (t < 256) {
        int wnc = t >> 7, cc = t & 127;
        float s = 0.f, q = 0.f;
#pragma unroll
        for (int m = 0; m < 4; ++m) {
            s += red[m * 2 + wnc][0][cc];
            q += red[m * 2 + wnc][1][cc];
        }
        atomicAdd(&stats[t], s);
        atomicAdd(&stats[256 + t], q);
    }
}

// ---------------- BN finalize ----------------
__global__ void finalize_kernel(const float* __restrict__ stats, const float* __restrict__ g,
                                const float* __restrict__ be, float* __restrict__ coef, float invN) {
    int c = threadIdx.x;
    float mean = stats[c] * invN;
    float var = stats[256 + c] * invN - mean * mean;
    float rs = rsqrtf(var + 1e-5f);
    float a = g[c] * rs;
    coef[c] = a;
    coef[256 + c] = be[c] - mean * a;
}

// ---------------- BN apply + ReLU, in-place on bf16 ----------------
__global__ __launch_bounds__(256) void bnrelu_ip_kernel(unsigned short* __restrict__ y,
                                                        const float* __restrict__ coef, int total) {
    int gid = blockIdx.x * 256 + threadIdx.x;
    if (gid >= total) return;
    int r = gid >> 5, s = gid & 31;
    size_t idx = (size_t)r * 256 + s * 8;
    uint4 v = *(const uint4*)(y + idx);
    float4 a0 = *(const float4*)(coef + s * 8);
    float4 a1 = *(const float4*)(coef + s * 8 + 4);
    float4 c0 = *(const float4*)(coef + 256 + s * 8);
    float4 c1 = *(const float4*)(coef + 256 + s * 8 + 4);
    unsigned int vv[4] = {v.x, v.y, v.z, v.w};
    float av[8] = {a0.x, a0.y, a0.z, a0.w, a1.x, a1.y, a1.z, a1.w};
    float cvf[8] = {c0.x, c0.y, c0.z, c0.w, c1.x, c1.y, c1.z, c1.w};
    unsigned int ov[4];
#pragma unroll
    for (int j = 0; j < 4; ++j) {
        float o0 = fmaxf(0.f, blo(vv[j]) * av[2 * j] + cvf[2 * j]);
        float o1 = fmaxf(0.f, bhi(vv[j]) * av[2 * j + 1] + cvf[2 * j + 1]);
        ov[j] = (unsigned int)f2b(o0) | ((unsigned int)f2b(o1) << 16);
    }
    uint4 o = {ov[0], ov[1], ov[2], ov[3]};
    *(uint4*)(y + idx) = o;
}

// ---------------- BN apply + ReLU, f32 output ----------------
__global__ __launch_bounds__(256) void bnrelu_out_kernel(const unsigned short* __restrict__ y,
                                                         const float* __restrict__ coef,
                                                         float* __restrict__ out, int total) {
    int gid = blockIdx.x * 256 + threadIdx.x;
    if (gid >= total) return;
    int r = gid >> 5, s = gid & 31;
    size_t idx = (size_t)r * 256 + s * 8;
    uint4 v = *(const uint4*)(y + idx);
    float4 a0 = *(const float4*)(coef + s * 8);
    float4 a1 = *(const float4*)(coef + s * 8 + 4);
    float4 c0 = *(const float4*)(coef + 256 + s * 8);
    float4 c1 = *(const float4*)(coef + 256 + s * 8 + 4);
    unsigned int vv[4] = {v.x, v.y, v.z, v.w};
    float av[8] = {a0.x, a0.y, a0.z, a0.w, a1.x, a1.y, a1.z, a1.w};
    float cvf[8] = {c0.x, c0.y, c0.z, c0.w, c1.x, c1.y, c1.z, c1.w};
    float o[8];
#pragma unroll
    for (int j = 0; j < 4; ++j) {
        o[2 * j]     = fmaxf(0.f, blo(vv[j]) * av[2 * j] + cvf[2 * j]);
        o[2 * j + 1] = fmaxf(0.f, bhi(vv[j]) * av[2 * j + 1] + cvf[2 * j + 1]);
    }
    float4 w0 = {o[0], o[1], o[2], o[3]};
    float4 w1 = {o[4], o[5], o[6], o[7]};
    *(float4*)(out + idx) = w0;
    *(float4*)(out + idx + 4) = w1;
}

extern "C" void kernel_launch(void* const* d_in, const int* in_sizes, int n_in,
                              void* d_out, int out_size, void* d_ws, size_t ws_size,
                              hipStream_t stream) {
    const float* x   = (const float*)d_in[0];
    const int*   er  = (const int*)d_in[1];
    const int*   ec  = (const int*)d_in[2];
    const float* ev  = (const float*)d_in[3];
    const float* eps = (const float*)d_in[4];
    const float* W1  = (const float*)d_in[5];
    const float* b1  = (const float*)d_in[6];
    const float* g1  = (const float*)d_in[7];
    const float* be1 = (const float*)d_in[8];
    const float* W2  = (const float*)d_in[9];
    const float* b2  = (const float*)d_in[10];
    const float* g2  = (const float*)d_in[11];
    const float* be2 = (const float*)d_in[12];

    const int N = in_sizes[0] / 256;      // 100000
    const int E = in_sizes[1];            // 3200000
    const int Npad = ((N + 127) / 128) * 128;

    char* ws = (char*)d_ws;
    size_t off = 0;
    auto alloc = [&](size_t bytes) { size_t cur = off; off = (off + bytes + 255) & ~(size_t)255; return cur; };
    size_t o_counts = alloc((size_t)N * 4);
    size_t o_cursor = alloc((size_t)N * 4);
    size_t o_stats  = alloc(4096);
    size_t zbytes   = off;                 // zero counts+cursor+stats each call
    size_t o_rowst  = alloc((size_t)(N + 1) * 4);
    size_t o_coef   = alloc(4096);
    size_t o_bsum   = alloc(1024);
    size_t o_cv     = alloc((size_t)E * 8);
    size_t o_xb     = alloc((size_t)N * 256 * 2);
    size_t o_h0     = alloc((size_t)Npad * 256 * 2);
    size_t o_y1     = alloc((size_t)Npad * 256 * 2);
    size_t o_w1t    = alloc(65536 * 2);
    size_t o_w2t    = alloc(65536 * 2);
    (void)ws_size;

    int* counts = (int*)(ws + o_counts);
    int* cursor = (int*)(ws + o_cursor);
    float* stats = (float*)(ws + o_stats);
    int* row_start = (int*)(ws + o_rowst);
    float* coef = (float*)(ws + o_coef);
    int* bsum = (int*)(ws + o_bsum);
    int2* cv = (int2*)(ws + o_cv);
    unsigned short* xb = (unsigned short*)(ws + o_xb);
    unsigned short* h0 = (unsigned short*)(ws + o_h0);
    unsigned short* y1 = (unsigned short*)(ws + o_y1);
    unsigned short* w1t = (unsigned short*)(ws + o_w1t);
    unsigned short* w2t = (unsigned short*)(ws + o_w2t);

    hipMemsetAsync(ws, 0, zbytes, stream);

    int total8 = N * 32;
    int nconv = (total8 + 255) / 256;
    int nhist = 2048;
    prep_kernel<<<nconv + 512 + nhist, 256, 0, stream>>>(x, xb, total8, W1, W2, w1t, w2t,
                                                         er, counts, E, nconv, nhist);

    int nb = (N + 1023) / 1024;
    scan1_kernel<<<nb, 256, 0, stream>>>(counts, bsum, N);
    scan2_kernel<<<1, 64, 0, stream>>>(bsum, nb);
    scan3_kernel<<<nb, 256, 0, stream>>>(counts, bsum, row_start, N);
    scatter_kernel<<<2048, 256, 0, stream>>>(er, ec, ev, row_start, cursor, cv, E);

    spmm_kernel<<<(N + 3) / 4, 256, 0, stream>>>(xb, cv, row_start, counts, eps, h0, N);

    float invN = 1.0f / (float)N;
    gemm_bn_kernel<<<Npad / 128, 512, 0, stream>>>(h0, w1t, b1, y1, stats, N);
    finalize_kernel<<<1, 256, 0, stream>>>(stats, g1, be1, coef, invN);
    bnrelu_ip_kernel<<<(total8 + 255) / 256, 256, 0, stream>>>(y1, coef, total8);

    gemm_bn_kernel<<<Npad / 128, 512, 0, stream>>>(y1, w2t, b2, h0, stats + 512, N);
    finalize_kernel<<<1, 256, 0, stream>>>(stats + 512, g2, be2, coef + 512, invN);
    bnrelu_out_kernel<<<(total8 + 255) / 256, 256, 0, stream>>>(h0, coef + 512, (float*)d_out, total8);
}

// Round 3
// 616.210 us; speedup vs baseline: 1.3530x; 1.1996x over previous
//
#include <hip/hip_runtime.h>

typedef float f32x4 __attribute__((ext_vector_type(4)));
typedef __bf16 bf16x8 __attribute__((ext_vector_type(8)));

#define NBIN_MAX 1024
#define CH 10240

__device__ __forceinline__ float b2f(unsigned short u) {
    union { unsigned int i; float f; } v; v.i = ((unsigned int)u) << 16; return v.f;
}
__device__ __forceinline__ unsigned short f2b(float f) {
    unsigned int x = __float_as_uint(f);
    unsigned int r = x + 0x7FFFu + ((x >> 16) & 1u);
    return (unsigned short)(r >> 16);
}
__device__ __forceinline__ float blo(unsigned int d) { return __uint_as_float(d << 16); }
__device__ __forceinline__ float bhi(unsigned int d) { return __uint_as_float(d & 0xffff0000u); }

__device__ __forceinline__ void gload_lds16(const void* g, void* l) {
    __builtin_amdgcn_global_load_lds((const __attribute__((address_space(1))) void*)g,
                                     (__attribute__((address_space(3))) void*)l, 16, 0, 0);
}

// ---------------- fused prep: x->bf16 | W->bf16 transposed | row histogram ----------------
__global__ __launch_bounds__(256) void prep_kernel(const float* __restrict__ x, unsigned short* __restrict__ xb, int total8,
                                                   const float* __restrict__ W1, const float* __restrict__ W2,
                                                   unsigned short* __restrict__ w1t, unsigned short* __restrict__ w2t,
                                                   const int* __restrict__ er, int* __restrict__ counts, int E,
                                                   int nconv, int nhist) {
    int b = blockIdx.x, t = threadIdx.x;
    if (b < nconv) {
        int gid = b * 256 + t;
        if (gid >= total8) return;
        size_t idx = (size_t)gid * 8;
        float4 v0 = *(const float4*)(x + idx);
        float4 v1 = *(const float4*)(x + idx + 4);
        ushort4 o0, o1;
        o0.x = f2b(v0.x); o0.y = f2b(v0.y); o0.z = f2b(v0.z); o0.w = f2b(v0.w);
        o1.x = f2b(v1.x); o1.y = f2b(v1.y); o1.z = f2b(v1.z); o1.w = f2b(v1.w);
        *(ushort4*)(xb + idx) = o0;
        *(ushort4*)(xb + idx + 4) = o1;
    } else if (b < nconv + 512) {
        int gid = (b - nconv) * 256 + t;
        int which = gid >> 16;
        int idx = gid & 65535;
        int n = idx >> 8, k = idx & 255;
        const float* W = which ? W2 : W1;
        unsigned short* O = which ? w2t : w1t;
        O[n * 256 + k] = f2b(W[k * 256 + n]);
    } else {
        int e0 = (b - nconv - 512) * 256 + t;
        int step = nhist * 256;
        for (int e = e0; e < E; e += step)
            atomicAdd(&counts[er[e]], 1);
    }
}

// ---------------- scan (row_start from counts) ----------------
__global__ __launch_bounds__(256) void scan1_kernel(const int* __restrict__ counts, int* __restrict__ bsum, int N) {
    int base = blockIdx.x * 1024;
    int t = threadIdx.x, lane = t & 63, w = t >> 6;
    int s = 0;
#pragma unroll
    for (int j = 0; j < 4; ++j) {
        int idx = base + t * 4 + j;
        s += (idx < N) ? counts[idx] : 0;
    }
#pragma unroll
    for (int off = 1; off < 64; off <<= 1) s += __shfl_xor(s, off);
    __shared__ int red[4];
    if (lane == 0) red[w] = s;
    __syncthreads();
    if (t == 0) bsum[blockIdx.x] = red[0] + red[1] + red[2] + red[3];
}

__global__ void scan2_kernel(int* __restrict__ bsum, int nb) {
    if (blockIdx.x == 0 && threadIdx.x == 0) {
        int acc = 0;
        for (int i = 0; i < nb; ++i) { int v = bsum[i]; bsum[i] = acc; acc += v; }
    }
}

__global__ __launch_bounds__(256) void scan3_kernel(const int* __restrict__ counts, const int* __restrict__ bsum,
                                                    int* __restrict__ row_start, int N) {
    int base = blockIdx.x * 1024;
    int t = threadIdx.x, lane = t & 63, w = t >> 6;
    int v[4]; int s = 0;
#pragma unroll
    for (int j = 0; j < 4; ++j) {
        int idx = base + t * 4 + j;
        v[j] = (idx < N) ? counts[idx] : 0;
        s += v[j];
    }
    int sinc = s;
#pragma unroll
    for (int off = 1; off < 64; off <<= 1) {
        int u = __shfl_up(sinc, off);
        if (lane >= off) sinc += u;
    }
    __shared__ int wsum[4];
    if (lane == 63) wsum[w] = sinc;
    __syncthreads();
    int woff = 0;
    for (int i = 0; i < w; ++i) woff += wsum[i];
    int excl = bsum[blockIdx.x] + woff + (sinc - s);
#pragma unroll
    for (int j = 0; j < 4; ++j) {
        int idx = base + t * 4 + j;
        if (idx < N) row_start[idx] = excl;
        excl += v[j];
    }
}

// ---------------- bin cursors init: bin_cursor[b] = row_start[b*128] ----------------
__global__ __launch_bounds__(256) void initbins_kernel(const int* __restrict__ row_start,
                                                       int* __restrict__ bin_cursor, int N, int nbin) {
    int b = blockIdx.x * 256 + threadIdx.x;
    if (b < nbin) bin_cursor[b] = row_start[b * 128];
}

// ---------------- scatter pass 1: LDS-staged coarse binning (bin = row>>7) ----------------
// Packs (lrow<<20 | col, val_bits) into int2; writes bin-grouped bursts.
__global__ __launch_bounds__(512) void scatter1_kernel(const int* __restrict__ er, const int* __restrict__ ec,
                                                       const float* __restrict__ ev, int* __restrict__ bin_cursor,
                                                       int2* __restrict__ cvt, int E, int nbin) {
    __shared__ int hist[NBIN_MAX];
    __shared__ int lstart[NBIN_MAX];
    __shared__ int gbase[NBIN_MAX];
    __shared__ int lcur[NBIN_MAX];
    __shared__ int2 stage[CH];
    __shared__ unsigned short binof[CH];
    __shared__ int wsum[8];

    const int t = threadIdx.x;
    const int e0 = blockIdx.x * CH;
    const int ecnt = min(CH, E - e0);

    for (int i = t; i < nbin; i += 512) hist[i] = 0;
    __syncthreads();
    // phase A: local histogram
    for (int i = t; i < ecnt; i += 512)
        atomicAdd(&hist[er[e0 + i] >> 7], 1);
    __syncthreads();
    // phase B: exclusive scan of hist (pairs: thread t owns bins 2t, 2t+1)
    {
        int lane = t & 63, w = t >> 6;
        int a = (2 * t < nbin) ? hist[2 * t] : 0;
        int b2 = (2 * t + 1 < nbin) ? hist[2 * t + 1] : 0;
        int s = a + b2;
        int inc = s;
#pragma unroll
        for (int off = 1; off < 64; off <<= 1) {
            int u = __shfl_up(inc, off);
            if (lane >= off) inc += u;
        }
        if (lane == 63) wsum[w] = inc;
        __syncthreads();
        int woff = 0;
        for (int i = 0; i < w; ++i) woff += wsum[i];
        int excl = woff + inc - s;
        if (2 * t < nbin) { lstart[2 * t] = excl; lcur[2 * t] = excl; }
        if (2 * t + 1 < nbin) { lstart[2 * t + 1] = excl + a; lcur[2 * t + 1] = excl + a; }
    }
    // phase B2: reserve global ranges
    for (int i = t; i < nbin; i += 512) {
        int h = hist[i];
        gbase[i] = h ? atomicAdd(&bin_cursor[i], h) : 0;
    }
    __syncthreads();
    // phase C: regroup into LDS by bin
    for (int i = t; i < ecnt; i += 512) {
        int r = er[e0 + i], c = ec[e0 + i];
        float v = ev[e0 + i];
        int bin = r >> 7;
        int q = atomicAdd(&lcur[bin], 1);
        stage[q] = make_int2(c | ((r & 127) << 20), __float_as_int(v));
        binof[q] = (unsigned short)bin;
    }
    __syncthreads();
    // phase D: burst writeout (consecutive q in same bin -> consecutive global)
    for (int q = t; q < ecnt; q += 512) {
        int bin = binof[q];
        int gpos = gbase[bin] + (q - lstart[bin]);
        cvt[gpos] = stage[q];
    }
}

// ---------------- scatter pass 2: exact row sort within each 128-row bin ----------------
__global__ __launch_bounds__(256) void scatter2_kernel(const int2* __restrict__ cvt, const int* __restrict__ row_start,
                                                       int2* __restrict__ cv, int E, int N, int nbin) {
    __shared__ int lcur[128];
    const int b = blockIdx.x, t = threadIdx.x;
    const int r0 = b * 128;
    const int estart = row_start[r0];
    const int next = r0 + 128;
    const int eend = (next < N) ? row_start[next] : E;
    if (t < 128) {
        int r = r0 + t;
        lcur[t] = (r < N) ? row_start[r] : 0;
    }
    __syncthreads();
    for (int i = estart + t; i < eend; i += 256) {
        int2 d = cvt[i];
        int lrow = d.x >> 20;
        int pos = atomicAdd(&lcur[lrow], 1);
        cv[pos] = make_int2(d.x & 0xFFFFF, d.y);
    }
}

// ---------------- SpMM + self-loop: h0 = (1+eps)*x + A@x  (bf16 out) ----------------
#define ACC4(d, v) { a0 += (v) * blo((d).x); a1 += (v) * bhi((d).x); \
                     a2 += (v) * blo((d).y); a3 += (v) * bhi((d).y); }

__global__ __launch_bounds__(256) void spmm_kernel(const unsigned short* __restrict__ xb, const int2* __restrict__ cv,
                                                   const int* __restrict__ row_start, const int* __restrict__ counts,
                                                   const float* __restrict__ epsp, unsigned short* __restrict__ h0, int N) {
    int node = blockIdx.x * 4 + (threadIdx.x >> 6);
    int lane = threadIdx.x & 63;
    if (node >= N) return;
    int start = __builtin_amdgcn_readfirstlane(row_start[node]);
    int deg   = __builtin_amdgcn_readfirstlane(counts[node]);
    const char* xbb = (const char*)xb;
    int voff = lane * 8;
    float a0 = 0.f, a1 = 0.f, a2 = 0.f, a3 = 0.f;

    for (int base = 0; base < deg; base += 64) {
        int rem = deg - base; if (rem > 64) rem = 64;
        int2 my = make_int2(0, 0);
        if (lane < rem) my = cv[start + base + lane];
        int j = 0;
        for (; j + 4 <= rem; j += 4) {
            int c0 = __builtin_amdgcn_readlane(my.x, j + 0);
            int c1 = __builtin_amdgcn_readlane(my.x, j + 1);
            int c2 = __builtin_amdgcn_readlane(my.x, j + 2);
            int c3 = __builtin_amdgcn_readlane(my.x, j + 3);
            float v0 = __int_as_float(__builtin_amdgcn_readlane(my.y, j + 0));
            float v1 = __int_as_float(__builtin_amdgcn_readlane(my.y, j + 1));
            float v2 = __int_as_float(__builtin_amdgcn_readlane(my.y, j + 2));
            float v3 = __int_as_float(__builtin_amdgcn_readlane(my.y, j + 3));
            uint2 d0 = *(const uint2*)(xbb + (size_t)c0 * 512 + voff);
            uint2 d1 = *(const uint2*)(xbb + (size_t)c1 * 512 + voff);
            uint2 d2 = *(const uint2*)(xbb + (size_t)c2 * 512 + voff);
            uint2 d3 = *(const uint2*)(xbb + (size_t)c3 * 512 + voff);
            ACC4(d0, v0); ACC4(d1, v1); ACC4(d2, v2); ACC4(d3, v3);
        }
        for (; j < rem; ++j) {
            int c0 = __builtin_amdgcn_readlane(my.x, j);
            float v0 = __int_as_float(__builtin_amdgcn_readlane(my.y, j));
            uint2 d0 = *(const uint2*)(xbb + (size_t)c0 * 512 + voff);
            ACC4(d0, v0);
        }
    }

    float ep = 1.0f + epsp[0];
    uint2 xo = *(const uint2*)(xbb + (size_t)node * 512 + voff);
    unsigned int w0 = ((unsigned int)f2b(ep * blo(xo.x) + a0)) | (((unsigned int)f2b(ep * bhi(xo.x) + a1)) << 16);
    unsigned int w1 = ((unsigned int)f2b(ep * blo(xo.y) + a2)) | (((unsigned int)f2b(ep * bhi(xo.y) + a3)) << 16);
    *(uint2*)((char*)h0 + (size_t)node * 512 + voff) = make_uint2(w0, w1);
}

// ---------------- GEMM (bf16 MFMA) + bias + BN-stat accumulation ----------------
__global__ __launch_bounds__(512, 4) void gemm_bn_kernel(const unsigned short* __restrict__ A,
                                                         const unsigned short* __restrict__ Wt,
                                                         const float* __restrict__ bias,
                                                         unsigned short* __restrict__ Y,
                                                         float* __restrict__ stats, int N) {
    __shared__ unsigned short As[128 * 64];
    __shared__ unsigned short Bs[256 * 64];
    __shared__ float red[8][2][128];

    const int t = threadIdx.x, lane = t & 63, w = t >> 6;
    const int wm = w >> 1, wn = w & 1;
    const long row0 = (long)blockIdx.x * 128;

    f32x4 acc[2][8];
#pragma unroll
    for (int i = 0; i < 2; ++i)
#pragma unroll
        for (int j = 0; j < 8; ++j) acc[i][j] = (f32x4){0.f, 0.f, 0.f, 0.f};

    const int lr = lane >> 3;
    const int cb0 = (lane & 7) << 4;

    for (int ks = 0; ks < 4; ++ks) {
        if (ks) __syncthreads();
#pragma unroll
        for (int i = 0; i < 2; ++i) {
            int chunk = w * 2 + i;
            int r = chunk * 8 + lr;
            int sb = cb0 ^ ((r & 7) << 4);
            gload_lds16(A + (row0 + r) * 256 + ks * 64 + (sb >> 1), (char*)As + chunk * 1024);
        }
#pragma unroll
        for (int i = 0; i < 4; ++i) {
            int chunk = w * 4 + i;
            int n = chunk * 8 + lr;
            int sb = cb0 ^ ((n & 7) << 4);
            gload_lds16(Wt + n * 256 + ks * 64 + (sb >> 1), (char*)Bs + chunk * 1024);
        }
        __syncthreads();
#pragma unroll
        for (int k2 = 0; k2 < 2; ++k2) {
            int cb = k2 * 64 + ((lane >> 4) << 4);
            bf16x8 af[2];
#pragma unroll
            for (int mf = 0; mf < 2; ++mf) {
                int r = wm * 32 + mf * 16 + (lane & 15);
                af[mf] = *(const bf16x8*)((const char*)As + r * 128 + (cb ^ ((r & 7) << 4)));
            }
#pragma unroll
            for (int nf = 0; nf < 8; ++nf) {
                int n = wn * 128 + nf * 16 + (lane & 15);
                bf16x8 bfr = *(const bf16x8*)((const char*)Bs + n * 128 + (cb ^ ((n & 7) << 4)));
                acc[0][nf] = __builtin_amdgcn_mfma_f32_16x16x32_bf16(af[0], bfr, acc[0][nf], 0, 0, 0);
                acc[1][nf] = __builtin_amdgcn_mfma_f32_16x16x32_bf16(af[1], bfr, acc[1][nf], 0, 0, 0);
            }
        }
    }

    float csum[8], csq[8];
#pragma unroll
    for (int nf = 0; nf < 8; ++nf) { csum[nf] = 0.f; csq[nf] = 0.f; }
#pragma unroll
    for (int nf = 0; nf < 8; ++nf) {
        int col = wn * 128 + nf * 16 + (lane & 15);
        float b = bias[col];
#pragma unroll
        for (int mf = 0; mf < 2; ++mf) {
#pragma unroll
            for (int reg = 0; reg < 4; ++reg) {
                long r = row0 + wm * 32 + mf * 16 + ((lane >> 4) << 2) + reg;
                if (r < N) {
                    float y = acc[mf][nf][reg] + b;
                    Y[r * 256 + col] = f2b(y);
                    csum[nf] += y;
                    csq[nf] += y * y;
                }
            }
        }
    }
#pragma unroll
    for (int nf = 0; nf < 8; ++nf) {
        csum[nf] += __shfl_xor(csum[nf], 16);
        csum[nf] += __shfl_xor(csum[nf], 32);
        csq[nf] += __shfl_xor(csq[nf], 16);
        csq[nf] += __shfl_xor(csq[nf], 32);
    }
    if (lane < 16) {
#pragma unroll
        for (int nf = 0; nf < 8; ++nf) {
            red[w][0][nf * 16 + lane] = csum[nf];
            red[w][1][nf * 16 + lane] = csq[nf];
        }
    }
    __syncthreads();
    if (t < 256) {
        int wnc = t >> 7, cc = t & 127;
        float s = 0.f, q = 0.f;
#pragma unroll
        for (int m = 0; m < 4; ++m) {
            s += red[m * 2 + wnc][0][cc];
            q += red[m * 2 + wnc][1][cc];
        }
        atomicAdd(&stats[t], s);
        atomicAdd(&stats[256 + t], q);
    }
}

// ---------------- BN finalize ----------------
__global__ void finalize_kernel(const float* __restrict__ stats, const float* __restrict__ g,
                                const float* __restrict__ be, float* __restrict__ coef, float invN) {
    int c = threadIdx.x;
    float mean = stats[c] * invN;
    float var = stats[256 + c] * invN - mean * mean;
    float rs = rsqrtf(var + 1e-5f);
    float a = g[c] * rs;
    coef[c] = a;
    coef[256 + c] = be[c] - mean * a;
}

// ---------------- BN apply + ReLU, in-place on bf16 ----------------
__global__ __launch_bounds__(256) void bnrelu_ip_kernel(unsigned short* __restrict__ y,
                                                        const float* __restrict__ coef, int total) {
    int gid = blockIdx.x * 256 + threadIdx.x;
    if (gid >= total) return;
    int r = gid >> 5, s = gid & 31;
    size_t idx = (size_t)r * 256 + s * 8;
    uint4 v = *(const uint4*)(y + idx);
    float4 a0 = *(const float4*)(coef + s * 8);
    float4 a1 = *(const float4*)(coef + s * 8 + 4);
    float4 c0 = *(const float4*)(coef + 256 + s * 8);
    float4 c1 = *(const float4*)(coef + 256 + s * 8 + 4);
    unsigned int vv[4] = {v.x, v.y, v.z, v.w};
    float av[8] = {a0.x, a0.y, a0.z, a0.w, a1.x, a1.y, a1.z, a1.w};
    float cvf[8] = {c0.x, c0.y, c0.z, c0.w, c1.x, c1.y, c1.z, c1.w};
    unsigned int ov[4];
#pragma unroll
    for (int j = 0; j < 4; ++j) {
        float o0 = fmaxf(0.f, blo(vv[j]) * av[2 * j] + cvf[2 * j]);
        float o1 = fmaxf(0.f, bhi(vv[j]) * av[2 * j + 1] + cvf[2 * j + 1]);
        ov[j] = (unsigned int)f2b(o0) | ((unsigned int)f2b(o1) << 16);
    }
    uint4 o = {ov[0], ov[1], ov[2], ov[3]};
    *(uint4*)(y + idx) = o;
}

// ---------------- BN apply + ReLU, f32 output ----------------
__global__ __launch_bounds__(256) void bnrelu_out_kernel(const unsigned short* __restrict__ y,
                                                         const float* __restrict__ coef,
                                                         float* __restrict__ out, int total) {
    int gid = blockIdx.x * 256 + threadIdx.x;
    if (gid >= total) return;
    int r = gid >> 5, s = gid & 31;
    size_t idx = (size_t)r * 256 + s * 8;
    uint4 v = *(const uint4*)(y + idx);
    float4 a0 = *(const float4*)(coef + s * 8);
    float4 a1 = *(const float4*)(coef + s * 8 + 4);
    float4 c0 = *(const float4*)(coef + 256 + s * 8);
    float4 c1 = *(const float4*)(coef + 256 + s * 8 + 4);
    unsigned int vv[4] = {v.x, v.y, v.z, v.w};
    float av[8] = {a0.x, a0.y, a0.z, a0.w, a1.x, a1.y, a1.z, a1.w};
    float cvf[8] = {c0.x, c0.y, c0.z, c0.w, c1.x, c1.y, c1.z, c1.w};
    float o[8];
#pragma unroll
    for (int j = 0; j < 4; ++j) {
        o[2 * j]     = fmaxf(0.f, blo(vv[j]) * av[2 * j] + cvf[2 * j]);
        o[2 * j + 1] = fmaxf(0.f, bhi(vv[j]) * av[2 * j + 1] + cvf[2 * j + 1]);
    }
    float4 w0 = {o[0], o[1], o[2], o[3]};
    float4 w1 = {o[4], o[5], o[6], o[7]};
    *(float4*)(out + idx) = w0;
    *(float4*)(out + idx + 4) = w1;
}

extern "C" void kernel_launch(void* const* d_in, const int* in_sizes, int n_in,
                              void* d_out, int out_size, void* d_ws, size_t ws_size,
                              hipStream_t stream) {
    const float* x   = (const float*)d_in[0];
    const int*   er  = (const int*)d_in[1];
    const int*   ec  = (const int*)d_in[2];
    const float* ev  = (const float*)d_in[3];
    const float* eps = (const float*)d_in[4];
    const float* W1  = (const float*)d_in[5];
    const float* b1  = (const float*)d_in[6];
    const float* g1  = (const float*)d_in[7];
    const float* be1 = (const float*)d_in[8];
    const float* W2  = (const float*)d_in[9];
    const float* b2  = (const float*)d_in[10];
    const float* g2  = (const float*)d_in[11];
    const float* be2 = (const float*)d_in[12];

    const int N = in_sizes[0] / 256;      // 100000
    const int E = in_sizes[1];            // 3200000
    const int Npad = ((N + 127) / 128) * 128;
    const int nbin = (N + 127) >> 7;      // 782

    char* ws = (char*)d_ws;
    size_t off = 0;
    auto alloc = [&](size_t bytes) { size_t cur = off; off = (off + bytes + 255) & ~(size_t)255; return cur; };
    size_t o_counts = alloc((size_t)N * 4);
    size_t o_stats  = alloc(4096);
    size_t zbytes   = off;                 // zero counts+stats each call
    size_t o_rowst  = alloc((size_t)(N + 1) * 4);
    size_t o_coef   = alloc(4096);
    size_t o_bsum   = alloc(1024);
    size_t o_binc   = alloc(NBIN_MAX * 4);
    size_t o_cv     = alloc((size_t)E * 8);
    size_t o_xb     = alloc((size_t)N * 256 * 2);
    size_t o_h0     = alloc((size_t)Npad * 256 * 2);
    size_t o_y1     = alloc((size_t)Npad * 256 * 2);   // also aliases cvt (scatter temp)
    size_t o_w1t    = alloc(65536 * 2);
    size_t o_w2t    = alloc(65536 * 2);
    (void)ws_size;

    int* counts = (int*)(ws + o_counts);
    float* stats = (float*)(ws + o_stats);
    int* row_start = (int*)(ws + o_rowst);
    float* coef = (float*)(ws + o_coef);
    int* bsum = (int*)(ws + o_bsum);
    int* bin_cursor = (int*)(ws + o_binc);
    int2* cv = (int2*)(ws + o_cv);
    unsigned short* xb = (unsigned short*)(ws + o_xb);
    unsigned short* h0 = (unsigned short*)(ws + o_h0);
    unsigned short* y1 = (unsigned short*)(ws + o_y1);
    int2* cvt = (int2*)(ws + o_y1);        // alias: dead before gemm1 writes y1
    unsigned short* w1t = (unsigned short*)(ws + o_w1t);
    unsigned short* w2t = (unsigned short*)(ws + o_w2t);

    hipMemsetAsync(ws, 0, zbytes, stream);

    int total8 = N * 32;
    int nconv = (total8 + 255) / 256;
    int nhist = 2048;
    prep_kernel<<<nconv + 512 + nhist, 256, 0, stream>>>(x, xb, total8, W1, W2, w1t, w2t,
                                                         er, counts, E, nconv, nhist);

    int nb = (N + 1023) / 1024;
    scan1_kernel<<<nb, 256, 0, stream>>>(counts, bsum, N);
    scan2_kernel<<<1, 64, 0, stream>>>(bsum, nb);
    scan3_kernel<<<nb, 256, 0, stream>>>(counts, bsum, row_start, N);
    initbins_kernel<<<(nbin + 255) / 256, 256, 0, stream>>>(row_start, bin_cursor, N, nbin);

    scatter1_kernel<<<(E + CH - 1) / CH, 512, 0, stream>>>(er, ec, ev, bin_cursor, cvt, E, nbin);
    scatter2_kernel<<<nbin, 256, 0, stream>>>(cvt, row_start, cv, E, N, nbin);

    spmm_kernel<<<(N + 3) / 4, 256, 0, stream>>>(xb, cv, row_start, counts, eps, h0, N);

    float invN = 1.0f / (float)N;
    gemm_bn_kernel<<<Npad / 128, 512, 0, stream>>>(h0, w1t, b1, y1, stats, N);
    finalize_kernel<<<1, 256, 0, stream>>>(stats, g1, be1, coef, invN);
    bnrelu_ip_kernel<<<(total8 + 255) / 256, 256, 0, stream>>>(y1, coef, total8);

    gemm_bn_kernel<<<Npad / 128, 512, 0, stream>>>(y1, w2t, b2, h0, stats + 512, N);
    finalize_kernel<<<1, 256, 0, stream>>>(stats + 512, g2, be2, coef + 512, invN);
    bnrelu_out_kernel<<<(total8 + 255) / 256, 256, 0, stream>>>(h0, coef + 512, (float*)d_out, total8);
}